// Round 6
// baseline (4191.724 us; speedup 1.0000x reference)
//
#include <hip/hip_runtime.h>

#define TT 2048
#define BQ 512
#define LAYERS 10
#define NC 7

__device__ __forceinline__ float sigm(float z) {
  return __builtin_amdgcn_rcpf(1.0f + __expf(-z));
}

// Wave-per-layer pipelined LSTM, R6.
// Block = 11 waves (704 thr): waves 0..9 = layers, wave 10 = FC+softmax+store.
// 2 batch elements per block, grid 256 = 1 block/CU.
// Lane layout (compute waves): lane = 2u+g, u=0..24, g in {0,1}.
//   g=0: gate rows i_u, g_u (both batches) + owns (u, batch A) c/h state.
//   g=1: gate rows f_u, o_u (both batches) + owns (u, batch B) c/h state.
// Gate exchange: __shfl_xor(.,1) -> DPP quad_perm. ONE barrier per step.
//
// KEY (R5 post-mortem): with VGPR_Count=84 the 100 weight floats were NOT
// register-resident -- the compiler rematerialized the loop-invariant global
// loads every step (L2-hit, invisible in FETCH_SIZE, ~4600 cyc/step of L2
// traffic). The empty asm "+v" below pins them into VGPRs: opaque output,
// cannot be rematerialized. Single-arg __launch_bounds__(704) caps VGPR at
// 168 (11 waves / 4 SIMDs = 3 waves/SIMD); need ~150.
__launch_bounds__(704)
__global__ void lstm_fused(const float* __restrict__ x,
                           const float* __restrict__ h0,
                           const float* __restrict__ c0,
                           const float* __restrict__ Wih,
                           const float* __restrict__ Whh,
                           const float* __restrict__ bias,
                           const float* __restrict__ fcw,
                           const float* __restrict__ fcb,
                           float* __restrict__ out) {
  // hs[parity][slot][.]: batch A at [0..24], batch B at [32..56].
  // slot 0 = x staging; slot l+1 = h of layer l.
  __shared__ __align__(16) float hs[2][LAYERS + 2][64];
  __shared__ float eb[16];  // FC-wave softmax exp staging

  const int tid = threadIdx.x;
  const int w = tid >> 6;          // wave index: 0..9 layers, 10 FC
  const int lane = tid & 63;
  const int bA = 2 * blockIdx.x;
  const bool comp = (w < LAYERS) && (lane < 50);
  const int g = lane & 1;          // 0: i,g rows + batch A; 1: f,o rows + batch B
  const int u = lane >> 1;         // unit 0..24

  float wi1[25], wi2[25], wh1[25], wh2[25];
  float b1 = 0.f, b2 = 0.f, c = 0.f;
  float xpre = 0.f;

  const bool isfc = (w == LAYERS) && (lane < 14);
  const int fcls = lane % NC;      // class
  const int fbat = lane / NC;      // 0=A, 1=B (junk for lane>=14)

#pragma unroll
  for (int k = 0; k < 25; ++k) { wi1[k] = 0.f; wi2[k] = 0.f; wh1[k] = 0.f; wh2[k] = 0.f; }

  if (comp) {
    const int r1 = g ? (u + 25) : u;        // f_u : i_u
    const int r2 = g ? (u + 75) : (u + 50); // o_u : g_u
    const float* pi1 = Wih + (w * 100 + r1) * 25;
    const float* pi2 = Wih + (w * 100 + r2) * 25;
    const float* ph1 = Whh + (w * 100 + r1) * 25;
    const float* ph2 = Whh + (w * 100 + r2) * 25;
#pragma unroll
    for (int k = 0; k < 25; ++k) {
      wi1[k] = pi1[k]; wi2[k] = pi2[k];
      wh1[k] = ph1[k]; wh2[k] = ph2[k];
    }
    b1 = bias[w * 100 + r1];
    b2 = bias[w * 100 + r2];
    const int bb = bA + g;                   // this lane's owned batch elem
    c = c0[(w * BQ + bb) * 25 + u];
    const float h00 = h0[(w * BQ + bb) * 25 + u];
    const int idx = g ? (32 + u) : u;
    hs[0][w + 1][idx] = h00;                 // both parities: first own-h read
    hs[1][w + 1][idx] = h00;
  } else if (isfc) {
#pragma unroll
    for (int k = 0; k < 25; ++k) wi1[k] = fcw[fcls * 25 + k];
    b1 = fcb[fcls];
  }
  if (w == 0 && lane < 50) {
    xpre = x[(size_t)bA * 25 + lane];        // x(t=0), 50 contiguous floats
  }

  // Pin weights into VGPRs: opaque identity, defeats rematerialization.
#pragma unroll
  for (int k = 0; k < 25; ++k) {
    asm volatile("" : "+v"(wi1[k]), "+v"(wi2[k]), "+v"(wh1[k]), "+v"(wh2[k]));
  }

  __syncthreads();

  const float s2 = g ? 1.0f : 2.0f;          // gate2: tanh (g) vs sigm (o)
  const float s2m1 = s2 - 1.0f;

  for (int s = 0; s < TT + LAYERS; ++s) {
    const int pr = (s & 1) ^ 1;              // read parity

    if (w < LAYERS) {
      const int t = s - w;                   // wave-uniform
      if ((unsigned)t < (unsigned)TT) {
        if (w == 0) {
          if (lane < 50) {
            // stage x(t) from prefetch reg; same-wave write->read ordered
            hs[pr][0][lane < 25 ? lane : lane + 7] = xpre;  // 32+(lane-25)
            if (s + 1 < TT)
              xpre = x[((size_t)(s + 1) * BQ + bA) * 25 + lane];
          }
        }
        if (lane < 50) {
          const float* ip = &hs[pr][w][0];       // input h (or x)
          const float* op = &hs[pr][w + 1][0];   // own h (self-written)
          float a1A = b1, a2A = b2, a1B = b1, a2B = b2;
          float h1A = 0.f, h2A = 0.f, h1B = 0.f, h2B = 0.f;
#pragma unroll
          for (int k = 0; k < 24; k += 4) {
            const float4 viA = *(const float4*)(ip + k);
            const float4 viB = *(const float4*)(ip + 32 + k);
            const float4 vhA = *(const float4*)(op + k);
            const float4 vhB = *(const float4*)(op + 32 + k);
            a1A += wi1[k+0]*viA.x; a1A += wi1[k+1]*viA.y; a1A += wi1[k+2]*viA.z; a1A += wi1[k+3]*viA.w;
            a2A += wi2[k+0]*viA.x; a2A += wi2[k+1]*viA.y; a2A += wi2[k+2]*viA.z; a2A += wi2[k+3]*viA.w;
            a1B += wi1[k+0]*viB.x; a1B += wi1[k+1]*viB.y; a1B += wi1[k+2]*viB.z; a1B += wi1[k+3]*viB.w;
            a2B += wi2[k+0]*viB.x; a2B += wi2[k+1]*viB.y; a2B += wi2[k+2]*viB.z; a2B += wi2[k+3]*viB.w;
            h1A += wh1[k+0]*vhA.x; h1A += wh1[k+1]*vhA.y; h1A += wh1[k+2]*vhA.z; h1A += wh1[k+3]*vhA.w;
            h2A += wh2[k+0]*vhA.x; h2A += wh2[k+1]*vhA.y; h2A += wh2[k+2]*vhA.z; h2A += wh2[k+3]*vhA.w;
            h1B += wh1[k+0]*vhB.x; h1B += wh1[k+1]*vhB.y; h1B += wh1[k+2]*vhB.z; h1B += wh1[k+3]*vhB.w;
            h2B += wh2[k+0]*vhB.x; h2B += wh2[k+1]*vhB.y; h2B += wh2[k+2]*vhB.z; h2B += wh2[k+3]*vhB.w;
          }
          {
            const float viA = ip[24], viB = ip[32 + 24];
            const float vhA = op[24], vhB = op[32 + 24];
            a1A += wi1[24]*viA; a2A += wi2[24]*viA;
            a1B += wi1[24]*viB; a2B += wi2[24]*viB;
            h1A += wh1[24]*vhA; h2A += wh2[24]*vhA;
            h1B += wh1[24]*vhB; h2B += wh2[24]*vhB;
          }
          const float p1A = a1A + h1A, p2A = a2A + h2A;
          const float p1B = a1B + h1B, p2B = a2B + h2B;

          const float G1A = sigm(p1A);                   // i_A (g=0) / f_A (g=1)
          const float G1B = sigm(p1B);
          const float G2A = s2 * sigm(s2 * p2A) - s2m1;  // g_A tanh / o_A sigm
          const float G2B = s2 * sigm(s2 * p2B) - s2m1;

          // exchange with lane^1 (DPP quad_perm): g=0 sends B-pair, gets (fA,oA);
          // g=1 sends A-pair, gets (iB,gB).
          const float q1 = __shfl_xor(g ? G1A : G1B, 1);
          const float q2 = __shfl_xor(g ? G2A : G2B, 1);

          const float iG = g ? q1 : G1A;
          const float gg = g ? q2 : G2A;
          const float fG = g ? G1B : q1;
          const float oG = g ? G2B : q2;
          c = fG * c + iG * gg;
          const float th = 2.0f * sigm(2.0f * c) - 1.0f;  // tanh(c)
          const float h = oG * th;
          hs[s & 1][w + 1][g ? (32 + u) : u] = h;
        }
      }
    } else {
      // ---- FC + softmax wave: t = s-10, reads h9 written last step
      const int t = s - LAYERS;
      if ((unsigned)t < (unsigned)TT && lane < 14) {
        const float* hp = &hs[pr][LAYERS][fbat * 32];
        float acc = b1;
#pragma unroll
        for (int k = 0; k < 24; k += 4) {
          const float4 v = *(const float4*)(hp + k);
          acc += wi1[k+0]*v.x; acc += wi1[k+1]*v.y; acc += wi1[k+2]*v.z; acc += wi1[k+3]*v.w;
        }
        acc += wi1[24] * hp[24];
        const float e = __expf(acc);           // logits small; no max-subtract
        eb[lane] = e;                          // same-wave LDS, lgkmcnt-ordered
        const float* ebb = eb + fbat * NC;
        const float ssum = ebb[0] + ebb[1] + ebb[2] + ebb[3] + ebb[4] + ebb[5] + ebb[6];
        out[((size_t)t * BQ + bA + fbat) * NC + fcls] =
            e * __builtin_amdgcn_rcpf(ssum);
      }
    }
    __syncthreads();  // the ONE barrier per step
  }
}

extern "C" void kernel_launch(void* const* d_in, const int* in_sizes, int n_in,
                              void* d_out, int out_size, void* d_ws, size_t ws_size,
                              hipStream_t stream) {
  const float* x   = (const float*)d_in[0];
  const float* h0  = (const float*)d_in[1];
  const float* c0  = (const float*)d_in[2];
  const float* Wih = (const float*)d_in[3];
  const float* Whh = (const float*)d_in[4];
  const float* b   = (const float*)d_in[5];
  const float* fcw = (const float*)d_in[6];
  const float* fcb = (const float*)d_in[7];
  float* out = (float*)d_out;

  lstm_fused<<<dim3(256), dim3(704), 0, stream>>>(x, h0, c0, Wih, Whh, b, fcw,
                                                  fcb, out);
}

// Round 7
// 4056.379 us; speedup vs baseline: 1.0334x; 1.0334x over previous
//
#include <hip/hip_runtime.h>

#define TT 2048
#define BQ 512
#define LAYERS 10
#define NC 7

typedef float v2f __attribute__((ext_vector_type(2)));

__device__ __forceinline__ float sigm(float z) {
  return __builtin_amdgcn_rcpf(1.0f + __expf(-z));
}

// R7: wave-per-layer pipelined LSTM, 1 batch element per block, 512 blocks,
// 2 blocks/CU co-resident (measured R1/R2: 2nd __launch_bounds__ arg = CUDA
// min-blocks: (640,2) -> 20 waves/CU -> 5 waves/SIMD -> 102-VGPR cap).
// Block = 10 waves; wave l = layer l; FC+softmax on wave 9's idle lanes 50-56
// (their unused whp[] registers hold the FC weights -> no extra VGPRs).
// Lane layout: lane = 2u+g, u=0..24. g=0 lane: rows i_u,g_u + owns c_u/h_u.
// g=1 lane: rows f_u,o_u. Gate pair exchanged via __shfl_xor(1) (DPP).
// Both rows' dots packed as v2f -> v_pk_fma_f32 (2 FMA/inst).
// ONE barrier per step.
__launch_bounds__(640, 2)
__global__ void lstm_fused(const float* __restrict__ x,
                           const float* __restrict__ h0,
                           const float* __restrict__ c0,
                           const float* __restrict__ Wih,
                           const float* __restrict__ Whh,
                           const float* __restrict__ bias,
                           const float* __restrict__ fcw,
                           const float* __restrict__ fcb,
                           float* __restrict__ out) {
  // hs[parity][slot][.]: slot 0 = x(t) staging, slot l+1 = h of layer l.
  __shared__ __align__(16) float hs[2][LAYERS + 2][32];
  __shared__ float eb[8];   // wave-9 softmax exp staging

  const int tid = threadIdx.x;
  const int w = tid >> 6;          // wave = layer (0..9)
  const int lane = tid & 63;
  const int b = blockIdx.x;        // batch element
  const int g = lane & 1;
  const int u = lane >> 1;
  const bool on = lane < 50;

  v2f wip[25], whp[25];            // weight pairs (row r1, row r2) per k
  v2f bia = {0.f, 0.f};
  float c = 0.f;
  float xpre = 0.f;

  const bool isfc = (w == 9) && (lane >= 50) && (lane < 50 + NC);
  const int fcls = lane - 50;

  if (on) {
    const int r1 = g ? (u + 25) : u;        // f_u : i_u
    const int r2 = g ? (u + 75) : (u + 50); // o_u : g_u
    const float* pi1 = Wih + (w * 100 + r1) * 25;
    const float* pi2 = Wih + (w * 100 + r2) * 25;
    const float* ph1 = Whh + (w * 100 + r1) * 25;
    const float* ph2 = Whh + (w * 100 + r2) * 25;
#pragma unroll
    for (int k = 0; k < 25; ++k) {
      wip[k] = (v2f){pi1[k], pi2[k]};
      whp[k] = (v2f){ph1[k], ph2[k]};
    }
    bia = (v2f){bias[w * 100 + r1], bias[w * 100 + r2]};
    if (g == 0) {
      c = c0[(w * BQ + b) * 25 + u];
      const float h00 = h0[(w * BQ + b) * 25 + u];
      hs[0][w + 1][u] = h00;   // both parities: valid first own-h read
      hs[1][w + 1][u] = h00;
    }
  } else if (isfc) {
    // FC weights overlay wave 9's unused whp[] regs (lanes 50..56)
#pragma unroll
    for (int k = 0; k < 25; ++k) whp[k].x = fcw[fcls * 25 + k];
    bia.x = fcb[fcls];
  }
  if (w == 0 && lane < 25) {
    xpre = x[(size_t)b * 25 + lane];   // x(t=0)
  }
  __syncthreads();

  for (int s = 0; s < TT + LAYERS; ++s) {
    const int pr = (s & 1) ^ 1;        // read parity
    const int t = s - w;               // wave-uniform

    if ((unsigned)t < (unsigned)TT) {
      if (w == 0 && lane < 25) {
        // stage x(t); only wave 0 touches slot 0, same-wave write->read is
        // ordered by lgkmcnt (R5-verified pattern)
        hs[pr][0][lane] = xpre;
        if (s + 1 < TT) xpre = x[((size_t)(s + 1) * BQ + b) * 25 + lane];
      }
      if (on) {
        const float* ip = &hs[pr][w][0];       // input (x or h_{w-1})
        const float* op = &hs[pr][w + 1][0];   // own h (self-written)
        v2f ai = bia;          // W_ih dot (rows r1,r2) -> v_pk_fma_f32
        v2f ah = {0.f, 0.f};   // W_hh dot
#pragma unroll
        for (int kk = 0; kk < 24; kk += 4) {
          const float4 vi = *(const float4*)(ip + kk);
          const float4 vh = *(const float4*)(op + kk);
          ai += wip[kk + 0] * vi.x;  ah += whp[kk + 0] * vh.x;
          ai += wip[kk + 1] * vi.y;  ah += whp[kk + 1] * vh.y;
          ai += wip[kk + 2] * vi.z;  ah += whp[kk + 2] * vh.z;
          ai += wip[kk + 3] * vi.w;  ah += whp[kk + 3] * vh.w;
        }
        ai += wip[24] * ip[24];
        ah += whp[24] * op[24];
        const float p1 = ai.x + ah.x;
        const float p2 = ai.y + ah.y;

        // g=0: p1->i (sigm), p2->g (tanh). g=1: p1->f, p2->o (both sigm).
        const float s2 = g ? 1.0f : 2.0f;
        const float G1 = sigm(p1);
        const float G2 = s2 * sigm(s2 * p2) - (s2 - 1.0f);

        const float q1 = __shfl_xor(G1, 1);    // partner's pair
        const float q2 = __shfl_xor(G2, 1);

        if (g == 0) {                          // q1=f, q2=o
          c = q1 * c + G1 * G2;                // f*c + i*g
          const float th = 2.0f * sigm(2.0f * c) - 1.0f;   // tanh(c)
          hs[s & 1][w + 1][u] = q2 * th;       // h = o*tanh(c)
        }
      }
    }

    // ---- FC + softmax on wave 9 lanes 50..56 (t_fc = s-10); reads the
    // OTHER parity buffer of h9 (written at step s-1) -> no race with the
    // LSTM write above.
    if (isfc) {
      const int tf = s - LAYERS;
      if ((unsigned)tf < (unsigned)TT) {
        const float* hp = &hs[pr][LAYERS][0];
        float acc = bia.x;
#pragma unroll
        for (int kk = 0; kk < 24; kk += 4) {
          const float4 v = *(const float4*)(hp + kk);
          acc += whp[kk + 0].x * v.x;  acc += whp[kk + 1].x * v.y;
          acc += whp[kk + 2].x * v.z;  acc += whp[kk + 3].x * v.w;
        }
        acc += whp[24].x * hp[24];
        const float e = __expf(acc);           // logits small; no max-subtract
        eb[fcls] = e;                          // same-wave LDS, ordered
        const float ssum = eb[0] + eb[1] + eb[2] + eb[3] + eb[4] + eb[5] + eb[6];
        out[((size_t)tf * BQ + b) * NC + fcls] =
            e * __builtin_amdgcn_rcpf(ssum);
      }
    }
    __syncthreads();   // the ONE barrier per step
  }
}

extern "C" void kernel_launch(void* const* d_in, const int* in_sizes, int n_in,
                              void* d_out, int out_size, void* d_ws, size_t ws_size,
                              hipStream_t stream) {
  const float* x   = (const float*)d_in[0];
  const float* h0  = (const float*)d_in[1];
  const float* c0  = (const float*)d_in[2];
  const float* Wih = (const float*)d_in[3];
  const float* Whh = (const float*)d_in[4];
  const float* b   = (const float*)d_in[5];
  const float* fcw = (const float*)d_in[6];
  const float* fcb = (const float*)d_in[7];
  float* out = (float*)d_out;

  lstm_fused<<<dim3(512), dim3(640), 0, stream>>>(x, h0, c0, Wih, Whh, b, fcw,
                                                  fcb, out);
}

// Round 8
// 2972.369 us; speedup vs baseline: 1.4102x; 1.3647x over previous
//
#include <hip/hip_runtime.h>

#define TT 2048
#define BQ 512
#define LAYERS 10
#define NC 7

typedef _Float16 half2v __attribute__((ext_vector_type(2)));

__device__ __forceinline__ float sigm(float z) {
  return __builtin_amdgcn_rcpf(1.0f + __expf(-z));
}
// f32 += dot(f16x2, f16x2) -- v_dot2_f32_f16
__device__ __forceinline__ float dot2(unsigned w, unsigned v, float acc) {
  return __builtin_amdgcn_fdot2(__builtin_bit_cast(half2v, w),
                                __builtin_bit_cast(half2v, v), acc, false);
}
// RNE pack of two floats into f16x2 dword
__device__ __forceinline__ unsigned pkh2(float a, float b) {
  union { _Float16 h[2]; unsigned u; } z;
  z.h[0] = (_Float16)a; z.h[1] = (_Float16)b;
  return z.u;
}

// R8: wave-per-layer pipelined LSTM with f16-packed weights + v_dot2_f32_f16.
// WHY (R4-R7 post-mortem): allocator grants only ~80-96 VGPRs; the fp32
// weight set (100 floats/lane) never fit -> overflow re-fetched from L2
// every step (~200KB/CU/step ~= the 4ms plateau). f16 pairs: 52 dwords ->
// resident. h/x live in LDS as packed f16 pairs: 8 LDS reads/lane-step.
// Block = 11 waves (704 thr): wave l = layer l (lanes 0..49, lane=2u+g),
// wave 10 = FC+softmax. 1 batch elem/block, 512 blocks. ONE barrier/step.
// Gates: g=0 lane rows i_u,g_u (owns c_u,h_u); g=1 lane rows f_u,o_u;
// pair exchange via __shfl_xor(1); h-pair packing via __shfl_xor(2).
__launch_bounds__(704)
__global__ void lstm_fused(const float* __restrict__ x,
                           const float* __restrict__ h0,
                           const float* __restrict__ c0,
                           const float* __restrict__ Wih,
                           const float* __restrict__ Whh,
                           const float* __restrict__ bias,
                           const float* __restrict__ fcw,
                           const float* __restrict__ fcb,
                           float* __restrict__ out) {
  // hs[parity][slot][dword]: slot 0 = x(t), slot l+1 = h_l; 13 f16x2 dwords
  // used per slot, stride 16 (64B) keeps uint4 reads aligned.
  __shared__ __align__(16) unsigned hs[2][12][16];
  __shared__ float eb[8];   // FC softmax exp staging

  const int tid = threadIdx.x;
  const int w = tid >> 6;          // wave: 0..9 layers, 10 = FC
  const int lane = tid & 63;
  const int b = blockIdx.x;        // batch element
  const int g = lane & 1;
  const int u = lane >> 1;
  const bool on = (w < LAYERS) && (lane < 50);
  const bool isfc = (w == LAYERS) && (lane < NC);

  unsigned wi1p[13], wi2p[13], wh1p[13], wh2p[13];  // f16-pair weights
  float b1 = 0.f, b2 = 0.f, c = 0.f;
  float xa = 0.f, xb = 0.f;        // wave-0 x prefetch pair

  if (on) {
    const int r1 = g ? (u + 25) : u;        // f_u : i_u
    const int r2 = g ? (u + 75) : (u + 50); // o_u : g_u
    const float* pi1 = Wih + (w * 100 + r1) * 25;
    const float* pi2 = Wih + (w * 100 + r2) * 25;
    const float* ph1 = Whh + (w * 100 + r1) * 25;
    const float* ph2 = Whh + (w * 100 + r2) * 25;
#pragma unroll
    for (int j = 0; j < 13; ++j) {
      const int k0 = 2 * j, k1 = 2 * j + 1;
      const float e1 = (k1 < 25) ? pi1[k1] : 0.f;
      const float e2 = (k1 < 25) ? pi2[k1] : 0.f;
      const float e3 = (k1 < 25) ? ph1[k1] : 0.f;
      const float e4 = (k1 < 25) ? ph2[k1] : 0.f;
      wi1p[j] = pkh2(pi1[k0], e1);
      wi2p[j] = pkh2(pi2[k0], e2);
      wh1p[j] = pkh2(ph1[k0], e3);
      wh2p[j] = pkh2(ph2[k0], e4);
    }
    b1 = bias[w * 100 + r1];
    b2 = bias[w * 100 + r2];
    if (g == 0) c = c0[(w * BQ + b) * 25 + u];
  } else if (isfc) {
    const float* pf = fcw + lane * 25;
#pragma unroll
    for (int j = 0; j < 13; ++j) {
      const int k0 = 2 * j, k1 = 2 * j + 1;
      wh1p[j] = pkh2(pf[k0], (k1 < 25) ? pf[k1] : 0.f);
    }
    b1 = fcb[lane];
  }

  // h0 -> packed f16 pairs into both parities
  {
    float h00 = 0.f;
    if (on && g == 0) h00 = h0[(w * BQ + b) * 25 + u];
    const float hp = __shfl_xor(h00, 2);       // partner owner (u^1)
    if (on && (lane & 3) == 0) {               // even-u owners write pair j=u/2
      const unsigned pk = pkh2(h00, (u == 24) ? 0.f : hp);
      hs[0][w + 1][lane >> 2] = pk;
      hs[1][w + 1][lane >> 2] = pk;
    }
  }
  if (w == 0 && lane < 13) {                   // x(0) prefetch
    const float* xp = x + (size_t)b * 25;
    xa = xp[2 * lane];
    xb = (lane < 12) ? xp[2 * lane + 1] : 0.f;
  }
  __syncthreads();

  const float s2 = g ? 1.0f : 2.0f;            // gate2: tanh (g) vs sigm (o)
  const float s2m1 = s2 - 1.0f;

  for (int s = 0; s < TT + LAYERS; ++s) {
    const int pr = (s & 1) ^ 1;                // read parity

    if (w < LAYERS) {
      const int t = s - w;                     // wave-uniform
      if ((unsigned)t < (unsigned)TT) {
        if (w == 0 && lane < 13) {
          // stage x(t) (same-wave write->read, lgkmcnt-ordered), prefetch x(t+1)
          hs[pr][0][lane] = pkh2(xa, xb);
          if (s + 1 < TT) {
            const float* xp = x + ((size_t)(s + 1) * BQ + b) * 25;
            xa = xp[2 * lane];
            xb = (lane < 12) ? xp[2 * lane + 1] : 0.f;
          }
        }
        if (lane < 50) {
          const unsigned* ip = &hs[pr][w][0];       // input (x or h_{w-1})
          const unsigned* op = &hs[pr][w + 1][0];   // own h
          const uint4 I0 = *(const uint4*)(ip + 0);
          const uint4 I1 = *(const uint4*)(ip + 4);
          const uint4 I2 = *(const uint4*)(ip + 8);
          const unsigned I3 = ip[12];
          const uint4 O0 = *(const uint4*)(op + 0);
          const uint4 O1 = *(const uint4*)(op + 4);
          const uint4 O2 = *(const uint4*)(op + 8);
          const unsigned O3 = op[12];

          float a1 = b1, a2 = b2, h1 = 0.f, h2 = 0.f;
          a1 = dot2(wi1p[0],  I0.x, a1);  a2 = dot2(wi2p[0],  I0.x, a2);
          a1 = dot2(wi1p[1],  I0.y, a1);  a2 = dot2(wi2p[1],  I0.y, a2);
          a1 = dot2(wi1p[2],  I0.z, a1);  a2 = dot2(wi2p[2],  I0.z, a2);
          a1 = dot2(wi1p[3],  I0.w, a1);  a2 = dot2(wi2p[3],  I0.w, a2);
          a1 = dot2(wi1p[4],  I1.x, a1);  a2 = dot2(wi2p[4],  I1.x, a2);
          a1 = dot2(wi1p[5],  I1.y, a1);  a2 = dot2(wi2p[5],  I1.y, a2);
          a1 = dot2(wi1p[6],  I1.z, a1);  a2 = dot2(wi2p[6],  I1.z, a2);
          a1 = dot2(wi1p[7],  I1.w, a1);  a2 = dot2(wi2p[7],  I1.w, a2);
          a1 = dot2(wi1p[8],  I2.x, a1);  a2 = dot2(wi2p[8],  I2.x, a2);
          a1 = dot2(wi1p[9],  I2.y, a1);  a2 = dot2(wi2p[9],  I2.y, a2);
          a1 = dot2(wi1p[10], I2.z, a1);  a2 = dot2(wi2p[10], I2.z, a2);
          a1 = dot2(wi1p[11], I2.w, a1);  a2 = dot2(wi2p[11], I2.w, a2);
          a1 = dot2(wi1p[12], I3,   a1);  a2 = dot2(wi2p[12], I3,   a2);
          h1 = dot2(wh1p[0],  O0.x, h1);  h2 = dot2(wh2p[0],  O0.x, h2);
          h1 = dot2(wh1p[1],  O0.y, h1);  h2 = dot2(wh2p[1],  O0.y, h2);
          h1 = dot2(wh1p[2],  O0.z, h1);  h2 = dot2(wh2p[2],  O0.z, h2);
          h1 = dot2(wh1p[3],  O0.w, h1);  h2 = dot2(wh2p[3],  O0.w, h2);
          h1 = dot2(wh1p[4],  O1.x, h1);  h2 = dot2(wh2p[4],  O1.x, h2);
          h1 = dot2(wh1p[5],  O1.y, h1);  h2 = dot2(wh2p[5],  O1.y, h2);
          h1 = dot2(wh1p[6],  O1.z, h1);  h2 = dot2(wh2p[6],  O1.z, h2);
          h1 = dot2(wh1p[7],  O1.w, h1);  h2 = dot2(wh2p[7],  O1.w, h2);
          h1 = dot2(wh1p[8],  O2.x, h1);  h2 = dot2(wh2p[8],  O2.x, h2);
          h1 = dot2(wh1p[9],  O2.y, h1);  h2 = dot2(wh2p[9],  O2.y, h2);
          h1 = dot2(wh1p[10], O2.z, h1);  h2 = dot2(wh2p[10], O2.z, h2);
          h1 = dot2(wh1p[11], O2.w, h1);  h2 = dot2(wh2p[11], O2.w, h2);
          h1 = dot2(wh1p[12], O3,   h1);  h2 = dot2(wh2p[12], O3,   h2);

          const float p1 = a1 + h1;
          const float p2 = a2 + h2;
          const float G1 = sigm(p1);                    // i (g=0) / f (g=1)
          const float G2 = s2 * sigm(s2 * p2) - s2m1;   // tanh g / sigm o

          const float q1 = __shfl_xor(G1, 1);           // partner's pair
          const float q2 = __shfl_xor(G2, 1);

          if (g == 0) {                                 // q1=f, q2=o
            c = q1 * c + G1 * G2;                       // f*c + i*g
            const float th = 2.0f * sigm(2.0f * c) - 1.0f;
            const float h = q2 * th;                    // o * tanh(c)
            const float hp = __shfl_xor(h, 2);          // partner owner's h
            if ((lane & 3) == 0) {                      // even-u owners publish
              hs[s & 1][w + 1][lane >> 2] =
                  pkh2(h, (u == 24) ? 0.f : hp);
            }
          } else {
            __shfl_xor(0.f, 2);  // keep shfl lane-pairing well-defined
          }
        }
      }
    } else if (isfc) {
      // FC + softmax wave: t = s-10; h9 written at step s-1 (parity pr)
      const int tf = s - LAYERS;
      if ((unsigned)tf < (unsigned)TT) {
        const unsigned* hp = &hs[pr][LAYERS + 1 - 1][0];  // slot 10 = h9
        const uint4 H0 = *(const uint4*)(hp + 0);
        const uint4 H1 = *(const uint4*)(hp + 4);
        const uint4 H2 = *(const uint4*)(hp + 8);
        const unsigned H3 = hp[12];
        float acc = b1;
        acc = dot2(wh1p[0],  H0.x, acc);
        acc = dot2(wh1p[1],  H0.y, acc);
        acc = dot2(wh1p[2],  H0.z, acc);
        acc = dot2(wh1p[3],  H0.w, acc);
        acc = dot2(wh1p[4],  H1.x, acc);
        acc = dot2(wh1p[5],  H1.y, acc);
        acc = dot2(wh1p[6],  H1.z, acc);
        acc = dot2(wh1p[7],  H1.w, acc);
        acc = dot2(wh1p[8],  H2.x, acc);
        acc = dot2(wh1p[9],  H2.y, acc);
        acc = dot2(wh1p[10], H2.z, acc);
        acc = dot2(wh1p[11], H2.w, acc);
        acc = dot2(wh1p[12], H3,   acc);
        const float e = __expf(acc);            // logits small; no max-subtract
        eb[lane] = e;                           // same-wave LDS, ordered
        const float ssum = eb[0] + eb[1] + eb[2] + eb[3] + eb[4] + eb[5] + eb[6];
        out[((size_t)tf * BQ + b) * NC + lane] =
            e * __builtin_amdgcn_rcpf(ssum);
      }
    }
    __syncthreads();   // the ONE barrier per step
  }
}

extern "C" void kernel_launch(void* const* d_in, const int* in_sizes, int n_in,
                              void* d_out, int out_size, void* d_ws, size_t ws_size,
                              hipStream_t stream) {
  const float* x   = (const float*)d_in[0];
  const float* h0  = (const float*)d_in[1];
  const float* c0  = (const float*)d_in[2];
  const float* Wih = (const float*)d_in[3];
  const float* Whh = (const float*)d_in[4];
  const float* b   = (const float*)d_in[5];
  const float* fcw = (const float*)d_in[6];
  const float* fcb = (const float*)d_in[7];
  float* out = (float*)d_out;

  lstm_fused<<<dim3(512), dim3(704), 0, stream>>>(x, h0, c0, Wih, Whh, b, fcw,
                                                  fcb, out);
}